// Round 1
// baseline (648.392 us; speedup 1.0000x reference)
//
#include <hip/hip_runtime.h>
#include <cmath>

#define NN 8192
#define KK 64
#define DD 256
#define HH 128
#define SET0V 32
#define EE (NN*KK)

static constexpr size_t OFF_ADJ  = 0;
static constexpr size_t OFF_FEAT = (size_t)NN * NN;             // 67108864
static constexpr size_t OFF_PROB = OFF_FEAT + (size_t)NN * DD;  // 69206016
static constexpr size_t OFF_PAIR = OFF_PROB + (size_t)EE * 2;   // 70254592
static constexpr size_t OFF_BEF  = OFF_PAIR + (size_t)EE * 2;   // 71303168
static constexpr size_t OFF_AFT  = OFF_BEF + 1;                 // 71303169
static constexpr size_t OFF_LEFT = OFF_AFT + 1;                 // 71303170

// ---------------------------------------------------------------------------
// Zero the new_adj output region, copy feat to output, write the two scalars.
// ---------------------------------------------------------------------------
__global__ void k_fill(float4* __restrict__ out_adj,
                       const float4* __restrict__ feat,
                       float4* __restrict__ out_feat,
                       float* __restrict__ out_scal) {
  size_t i = (size_t)blockIdx.x * blockDim.x + threadIdx.x;
  size_t stride = (size_t)gridDim.x * blockDim.x;
  const size_t NADJ4 = (size_t)NN * NN / 4;
  for (size_t p = i; p < NADJ4; p += stride)
    out_adj[p] = make_float4(0.f, 0.f, 0.f, 0.f);
  const size_t NF4 = (size_t)NN * DD / 4;
  for (size_t p = i; p < NF4; p += stride)
    out_feat[p] = feat[p];
  if (i == 0) {
    out_scal[0] = 64.0f;  // before_edge_num = E / dst
    out_scal[1] = 32.0f;  // after_edge_num  = kept nonzeros / dst (all vals >= 0.1)
  }
}

// ---------------------------------------------------------------------------
// Stage W2 / prelu_a as doubles in workspace (tiny).
// ---------------------------------------------------------------------------
__global__ void k_prep(const float* __restrict__ W2, const float* __restrict__ pa,
                       double* __restrict__ cw0, double* __restrict__ cw1,
                       double* __restrict__ ca) {
  int j = threadIdx.x;
  if (j < HH) {
    cw0[j] = (double)W2[2 * j];
    cw1[j] = (double)W2[2 * j + 1];
    ca[j]  = (double)pa[j];
  }
}

// ---------------------------------------------------------------------------
// g = feat @ W1  in fp64.  [8192,256] x [256,128] -> [8192,128] doubles.
// Block = 128 threads (one per output col), 16 nodes per block, grid 512.
// ---------------------------------------------------------------------------
__global__ __launch_bounds__(128) void k_g(const float* __restrict__ feat,
                                           const float* __restrict__ W1,
                                           double* __restrict__ g) {
  __shared__ float sf[16 * DD];  // 16 KiB feat tile
  int j = threadIdx.x;           // 0..127
  int n0 = blockIdx.x * 16;
  const float4* fsrc = (const float4*)(feat + (size_t)n0 * DD);
  float4* fdst = (float4*)sf;
  for (int t = j; t < 16 * DD / 4; t += 128) fdst[t] = fsrc[t];
  __syncthreads();
  double acc[16];
#pragma unroll
  for (int n = 0; n < 16; n++) acc[n] = 0.0;
  for (int k = 0; k < DD; k += 4) {
    double w0 = (double)W1[(k + 0) * HH + j];
    double w1 = (double)W1[(k + 1) * HH + j];
    double w2 = (double)W1[(k + 2) * HH + j];
    double w3 = (double)W1[(k + 3) * HH + j];
#pragma unroll
    for (int n = 0; n < 16; n++) {
      float4 f = *(const float4*)&sf[n * DD + k];
      acc[n] += (double)f.x * w0;
      acc[n] += (double)f.y * w1;
      acc[n] += (double)f.z * w2;
      acc[n] += (double)f.w * w3;
    }
  }
  for (int n = 0; n < 16; n++) g[(size_t)(n0 + n) * HH + j] = acc[n];
}

// ---------------------------------------------------------------------------
// Per-edge MLP in fp64: one lane per edge, one wave per dst row.
// h = (g[r]+b1) - g[c]; PReLU; logits via W2; softmax -> p1 (f64 for sort),
// prob_arr (f32 out), pair_list (f32 out).
// ---------------------------------------------------------------------------
__global__ __launch_bounds__(256) void k_edge(
    const double* __restrict__ g, const int* __restrict__ nbr,
    const float* __restrict__ b1, const float* __restrict__ b2,
    const double* __restrict__ cw0, const double* __restrict__ cw1,
    const double* __restrict__ ca, double* __restrict__ p1d,
    float* __restrict__ out_prob, float* __restrict__ out_pair) {
  int wave = threadIdx.x >> 6;
  int lane = threadIdx.x & 63;
  int r = blockIdx.x * 4 + wave;
  __shared__ double grb[4][HH];
  grb[wave][lane]      = g[(size_t)r * HH + lane]      + (double)b1[lane];
  grb[wave][lane + 64] = g[(size_t)r * HH + lane + 64] + (double)b1[lane + 64];
  __syncthreads();
  int c = nbr[r * KK + lane];
  const double* gcp = g + (size_t)c * HH;
  double t0 = 0.0, t1 = 0.0;
#pragma unroll 4
  for (int j = 0; j < HH; j += 2) {
    double gc0 = gcp[j];
    double gc1 = gcp[j + 1];
    double h0 = grb[wave][j] - gc0;
    double h1 = grb[wave][j + 1] - gc1;
    h0 = h0 >= 0.0 ? h0 : ca[j] * h0;
    h1 = h1 >= 0.0 ? h1 : ca[j + 1] * h1;
    t0 += h0 * cw0[j];
    t0 += h1 * cw0[j + 1];
    t1 += h0 * cw1[j];
    t1 += h1 * cw1[j + 1];
  }
  double l0 = t0 + (double)b2[0];
  double l1 = t1 + (double)b2[1];
  double m = l0 > l1 ? l0 : l1;
  double e0 = exp(l0 - m), e1 = exp(l1 - m);
  double inv = 1.0 / (e0 + e1);
  size_t e = (size_t)r * KK + lane;
  p1d[e] = e1 * inv;
  *(float2*)(out_prob + 2 * e) = make_float2((float)(e0 * inv), (float)(e1 * inv));
  *(float2*)(out_pair + 2 * e) = make_float2((float)r, (float)c);
}

// ---------------------------------------------------------------------------
// Per-row stable rank of p1 (ascending, ties by index = jnp stable argsort),
// keep rank>=32, degree-normalize kept adj entries, emit left_row.
// One wave per row, 4 rows per block.
// ---------------------------------------------------------------------------
__global__ __launch_bounds__(256) void k_select(
    const double* __restrict__ p1d, const int* __restrict__ nbr,
    const float* __restrict__ adj, float* __restrict__ out_adj,
    float* __restrict__ out_left) {
  int wave = threadIdx.x >> 6;
  int lane = threadIdx.x & 63;
  int r = blockIdx.x * 4 + wave;
  __shared__ double sp[4][64];
  __shared__ double sv[4][64];
  double p = p1d[(size_t)r * KK + lane];
  sp[wave][lane] = p;
  int c = nbr[r * KK + lane];
  float v = adj[(size_t)r * NN + c];
  __syncthreads();
  int rank = 0;
#pragma unroll 8
  for (int j = 0; j < 64; j++) {
    double q = sp[wave][j];
    rank += (int)((q < p) || (q == p && j < lane));
  }
  bool kept = rank >= SET0V;
  sv[wave][lane] = kept ? (double)v : 0.0;
  __syncthreads();
  double deg = 0.0;
#pragma unroll 8
  for (int j = 0; j < 64; j++) deg += sv[wave][j];
  if (kept) {
    out_adj[(size_t)r * NN + c] = (float)((double)v / (deg + 1e-6));
    out_left[(size_t)r * SET0V + (rank - SET0V)] = (float)(r * KK + lane);
  }
}

extern "C" void kernel_launch(void* const* d_in, const int* in_sizes, int n_in,
                              void* d_out, int out_size, void* d_ws, size_t ws_size,
                              hipStream_t stream) {
  const float* adj  = (const float*)d_in[0];
  const float* feat = (const float*)d_in[1];
  const int*   nbr  = (const int*)d_in[2];
  const float* W1   = (const float*)d_in[4];
  const float* b1   = (const float*)d_in[5];
  const float* pa   = (const float*)d_in[6];
  const float* W2   = (const float*)d_in[7];
  const float* b2   = (const float*)d_in[8];
  float* out = (float*)d_out;

  double* g   = (double*)d_ws;               // 8192*128 doubles = 8 MiB
  double* p1d = g + (size_t)NN * HH;         // 524288 doubles   = 4 MiB
  double* cw0 = p1d + (size_t)EE;            // 128 doubles
  double* cw1 = cw0 + HH;
  double* ca  = cw1 + HH;

  hipLaunchKernelGGL(k_fill, dim3(4096), dim3(256), 0, stream,
                     (float4*)(out + OFF_ADJ), (const float4*)feat,
                     (float4*)(out + OFF_FEAT), out + OFF_BEF);
  hipLaunchKernelGGL(k_prep, dim3(1), dim3(128), 0, stream, W2, pa, cw0, cw1, ca);
  hipLaunchKernelGGL(k_g, dim3(512), dim3(128), 0, stream, feat, W1, g);
  hipLaunchKernelGGL(k_edge, dim3(2048), dim3(256), 0, stream,
                     g, nbr, b1, b2, cw0, cw1, ca,
                     p1d, out + OFF_PROB, out + OFF_PAIR);
  hipLaunchKernelGGL(k_select, dim3(2048), dim3(256), 0, stream,
                     p1d, nbr, adj, out + OFF_ADJ, out + OFF_LEFT);
}

// Round 2
// 528.707 us; speedup vs baseline: 1.2264x; 1.2264x over previous
//
#include <hip/hip_runtime.h>
#include <cmath>

#define NN 8192
#define KK 64
#define DD 256
#define HH 128
#define SET0V 32
#define EE (NN*KK)

static constexpr size_t OFF_ADJ  = 0;
static constexpr size_t OFF_FEAT = (size_t)NN * NN;             // 67108864
static constexpr size_t OFF_PROB = OFF_FEAT + (size_t)NN * DD;  // 69206016
static constexpr size_t OFF_PAIR = OFF_PROB + (size_t)EE * 2;   // 70254592
static constexpr size_t OFF_BEF  = OFF_PAIR + (size_t)EE * 2;   // 71303168
static constexpr size_t OFF_AFT  = OFF_BEF + 1;                 // 71303169
static constexpr size_t OFF_LEFT = OFF_AFT + 1;                 // 71303170

// ---------------------------------------------------------------------------
// k_g: g = feat @ W1 in fp64 ([8192,256]x[256,128] -> [8192,128] doubles),
// plus feat copy-out and the two scalar outputs.
// 1024 blocks x 128 threads, 8 rows per block.
// ---------------------------------------------------------------------------
__global__ __launch_bounds__(128) void k_g(const float* __restrict__ feat,
                                           const float* __restrict__ W1,
                                           double* __restrict__ g,
                                           float4* __restrict__ out_feat,
                                           float* __restrict__ out_scal) {
  __shared__ float sf[8 * DD];  // 8 KiB
  int j = threadIdx.x;          // 0..127 = output col
  int n0 = blockIdx.x * 8;
  const float4* fsrc = (const float4*)(feat + (size_t)n0 * DD);
  float4* fdst = (float4*)sf;
  float4* odst = out_feat + (size_t)n0 * DD / 4;
#pragma unroll
  for (int t = 0; t < 4; t++) {
    float4 v = fsrc[j + t * 128];
    fdst[j + t * 128] = v;
    odst[j + t * 128] = v;   // fused feat copy-out
  }
  if (blockIdx.x == 0 && j == 0) {
    out_scal[0] = 64.0f;  // before_edge_num
    out_scal[1] = 32.0f;  // after_edge_num (kept vals >= 0.1, never zero)
  }
  __syncthreads();
  double acc[8];
#pragma unroll
  for (int n = 0; n < 8; n++) acc[n] = 0.0;
  for (int k = 0; k < DD; k += 4) {
    double w0 = (double)W1[(k + 0) * HH + j];
    double w1 = (double)W1[(k + 1) * HH + j];
    double w2 = (double)W1[(k + 2) * HH + j];
    double w3 = (double)W1[(k + 3) * HH + j];
#pragma unroll
    for (int n = 0; n < 8; n++) {
      float4 f = *(const float4*)&sf[n * DD + k];
      acc[n] += (double)f.x * w0;
      acc[n] += (double)f.y * w1;
      acc[n] += (double)f.z * w2;
      acc[n] += (double)f.w * w3;
    }
  }
#pragma unroll
  for (int n = 0; n < 8; n++) g[(size_t)(n0 + n) * HH + j] = acc[n];
}

// ---------------------------------------------------------------------------
// k_edge: per-edge MLP in fp64. One wave per dst row; 16 lanes per edge
// (4 edges concurrently). lane = q*16+s: edge-slot q, dim-segment s
// (dims s*8 .. s*8+7). Coalesced dwordx4 gathers of g[c], butterfly
// reduction over 16 lanes, shfl-routed softmax with coalesced stores.
// ---------------------------------------------------------------------------
__global__ __launch_bounds__(256) void k_edge(
    const double* __restrict__ g, const int* __restrict__ nbr,
    const float* __restrict__ b1, const float* __restrict__ b2,
    const float* __restrict__ pa, const float* __restrict__ W2,
    double* __restrict__ p1d, float* __restrict__ out_prob,
    float* __restrict__ out_pair) {
  int wave = threadIdx.x >> 6;
  int lane = threadIdx.x & 63;
  int r = blockIdx.x * 4 + wave;
  int q = lane >> 4;   // edge slot 0..3
  int s = lane & 15;   // dim segment 0..15

  double grb[8], aa[8], w0c[8], w1c[8];
  const double* gr = g + (size_t)r * HH + s * 8;
#pragma unroll
  for (int d = 0; d < 8; d++) {
    int dim = s * 8 + d;
    grb[d] = gr[d] + (double)b1[dim];
    aa[d]  = (double)pa[dim];
    w0c[d] = (double)W2[2 * dim];
    w1c[d] = (double)W2[2 * dim + 1];
  }

  const int* nrow = nbr + r * KK;
  double st0 = 0.0, st1 = 0.0;
  for (int grp = 0; grp < 16; grp++) {
    int c = nrow[grp * 4 + q];
    const double* gc = g + (size_t)c * HH + s * 8;
    double t0 = 0.0, t1 = 0.0;
#pragma unroll
    for (int d = 0; d < 8; d++) {
      double h = grb[d] - gc[d];
      h = h >= 0.0 ? h : aa[d] * h;
      t0 += h * w0c[d];
      t1 += h * w1c[d];
    }
#pragma unroll
    for (int m = 1; m < 16; m <<= 1) {
      t0 += __shfl_xor(t0, m, 16);
      t1 += __shfl_xor(t1, m, 16);
    }
    if (s == grp) { st0 = t0; st1 = t1; }  // lane q*16+grp keeps edge grp*4+q
  }
  // lane L wants edge L = 4*(L>>2 as grp)... holder h = (L&3)*16 + (L>>2)
  int src = ((lane & 3) << 4) | (lane >> 2);
  double T0 = __shfl(st0, src, 64);
  double T1 = __shfl(st1, src, 64);
  double l0 = T0 + (double)b2[0];
  double l1 = T1 + (double)b2[1];
  double m = l0 > l1 ? l0 : l1;
  double e0 = exp(l0 - m), e1 = exp(l1 - m);
  double inv = 1.0 / (e0 + e1);
  size_t e = (size_t)r * KK + lane;
  int c = nrow[lane];
  p1d[e] = e1 * inv;
  *(float2*)(out_prob + 2 * e) = make_float2((float)(e0 * inv), (float)(e1 * inv));
  *(float2*)(out_pair + 2 * e) = make_float2((float)r, (float)c);
}

// ---------------------------------------------------------------------------
// k_adj: one block per row. Zero the 32 KB output row (stays dirty in L2),
// then rank p1 (stable ascending, ties by index), degree-normalize kept
// entries, scatter-store them into the still-resident row, emit left_row.
// ---------------------------------------------------------------------------
__global__ __launch_bounds__(256) void k_adj(
    const double* __restrict__ p1d, const int* __restrict__ nbr,
    const float* __restrict__ adj, float* __restrict__ out_adj,
    float* __restrict__ out_left) {
  int r = blockIdx.x;
  int t = threadIdx.x;
  float4* row4 = (float4*)(out_adj + (size_t)r * NN);
  float4 z = make_float4(0.f, 0.f, 0.f, 0.f);
#pragma unroll
  for (int i = 0; i < 8; i++) row4[t + i * 256] = z;

  __shared__ double sp[KK];
  __shared__ double sm[KK];
  double p = 0.0;
  float v = 0.f;
  int c = 0;
  if (t < KK) {
    p = p1d[(size_t)r * KK + t];
    sp[t] = p;
    c = nbr[r * KK + t];
    v = adj[(size_t)r * NN + c];
  }
  __syncthreads();  // sp visible; also orders the zero-stores before scatter
  int rank = 0;
  if (t < KK) {
#pragma unroll 8
    for (int j = 0; j < KK; j++) {
      double qq = sp[j];
      rank += (int)((qq < p) || (qq == p && j < t));
    }
    sm[t] = (rank >= SET0V) ? (double)v : 0.0;
  }
  __syncthreads();
  if (t < KK) {
    double deg = 0.0;
#pragma unroll 8
    for (int j = 0; j < KK; j++) deg += sm[j];
    if (rank >= SET0V) {
      out_adj[(size_t)r * NN + c] = (float)((double)v / (deg + 1e-6));
      out_left[(size_t)r * SET0V + (rank - SET0V)] = (float)(r * KK + t);
    }
  }
}

extern "C" void kernel_launch(void* const* d_in, const int* in_sizes, int n_in,
                              void* d_out, int out_size, void* d_ws, size_t ws_size,
                              hipStream_t stream) {
  const float* adj  = (const float*)d_in[0];
  const float* feat = (const float*)d_in[1];
  const int*   nbr  = (const int*)d_in[2];
  const float* W1   = (const float*)d_in[4];
  const float* b1   = (const float*)d_in[5];
  const float* pa   = (const float*)d_in[6];
  const float* W2   = (const float*)d_in[7];
  const float* b2   = (const float*)d_in[8];
  float* out = (float*)d_out;

  double* g   = (double*)d_ws;           // 8192*128 doubles = 8 MiB
  double* p1d = g + (size_t)NN * HH;     // 524288 doubles   = 4 MiB

  hipLaunchKernelGGL(k_g, dim3(1024), dim3(128), 0, stream,
                     feat, W1, g, (float4*)(out + OFF_FEAT), out + OFF_BEF);
  hipLaunchKernelGGL(k_edge, dim3(2048), dim3(256), 0, stream,
                     g, nbr, b1, b2, pa, W2,
                     p1d, out + OFF_PROB, out + OFF_PAIR);
  hipLaunchKernelGGL(k_adj, dim3(8192), dim3(256), 0, stream,
                     p1d, nbr, adj, out + OFF_ADJ, out + OFF_LEFT);
}

// Round 4
// 513.151 us; speedup vs baseline: 1.2635x; 1.0303x over previous
//
#include <hip/hip_runtime.h>
#include <cmath>

#define NN 8192
#define KK 64
#define DD 256
#define HH 128
#define SET0V 32
#define EE (NN*KK)

typedef float f4_t __attribute__((ext_vector_type(4)));

static constexpr size_t OFF_ADJ  = 0;
static constexpr size_t OFF_FEAT = (size_t)NN * NN;             // 67108864
static constexpr size_t OFF_PROB = OFF_FEAT + (size_t)NN * DD;  // 69206016
static constexpr size_t OFF_PAIR = OFF_PROB + (size_t)EE * 2;   // 70254592
static constexpr size_t OFF_BEF  = OFF_PAIR + (size_t)EE * 2;   // 71303168
static constexpr size_t OFF_AFT  = OFF_BEF + 1;                 // 71303169
static constexpr size_t OFF_LEFT = OFF_AFT + 1;                 // 71303170

// ---------------------------------------------------------------------------
// k_g: g = feat @ W1 in fp64 ([8192,256]x[256,128] -> [8192,128] doubles),
// plus feat copy-out (non-temporal) and the two scalar outputs.
// 1024 blocks x 128 threads, 8 rows per block.
// ---------------------------------------------------------------------------
__global__ __launch_bounds__(128) void k_g(const float* __restrict__ feat,
                                           const float* __restrict__ W1,
                                           double* __restrict__ g,
                                           f4_t* __restrict__ out_feat,
                                           float* __restrict__ out_scal) {
  __shared__ float sf[8 * DD];  // 8 KiB
  int j = threadIdx.x;          // 0..127 = output col
  int n0 = blockIdx.x * 8;
  const f4_t* fsrc = (const f4_t*)(feat + (size_t)n0 * DD);
  f4_t* fdst = (f4_t*)sf;
  f4_t* odst = out_feat + (size_t)n0 * DD / 4;
#pragma unroll
  for (int t = 0; t < 4; t++) {
    f4_t v = fsrc[j + t * 128];
    fdst[j + t * 128] = v;
    __builtin_nontemporal_store(v, odst + j + t * 128);  // fused feat copy-out
  }
  if (blockIdx.x == 0 && j == 0) {
    out_scal[0] = 64.0f;  // before_edge_num
    out_scal[1] = 32.0f;  // after_edge_num (kept vals >= 0.1, never zero)
  }
  __syncthreads();
  double acc[8];
#pragma unroll
  for (int n = 0; n < 8; n++) acc[n] = 0.0;
  for (int k = 0; k < DD; k += 4) {
    double w0 = (double)W1[(k + 0) * HH + j];
    double w1 = (double)W1[(k + 1) * HH + j];
    double w2 = (double)W1[(k + 2) * HH + j];
    double w3 = (double)W1[(k + 3) * HH + j];
#pragma unroll
    for (int n = 0; n < 8; n++) {
      f4_t f = *(const f4_t*)&sf[n * DD + k];
      acc[n] += (double)f.x * w0;
      acc[n] += (double)f.y * w1;
      acc[n] += (double)f.z * w2;
      acc[n] += (double)f.w * w3;
    }
  }
#pragma unroll
  for (int n = 0; n < 8; n++) g[(size_t)(n0 + n) * HH + j] = acc[n];
}

// ---------------------------------------------------------------------------
// k_edge: per-edge MLP in fp64, one wave per dst row, 16 lanes per edge.
// Fused: zero-fills the 32 KB new_adj row with interleaved non-temporal
// stores (pure write BW, hidden under gather latency — stores are never
// waited on). Writes d = l1-l0 (fp64) for ranking (strictly monotone in
// p1, identical order & ties), prob via fp32 expf, pair_list.
// ---------------------------------------------------------------------------
__global__ __launch_bounds__(256) void k_edge(
    const double* __restrict__ g, const int* __restrict__ nbr,
    const float* __restrict__ b1, const float* __restrict__ b2,
    const float* __restrict__ pa, const float* __restrict__ W2,
    double* __restrict__ p1d, float* __restrict__ out_prob,
    float* __restrict__ out_pair, float* __restrict__ out_adj) {
  int wave = threadIdx.x >> 6;
  int lane = threadIdx.x & 63;
  int r = blockIdx.x * 4 + wave;
  int q = lane >> 4;   // edge slot 0..3
  int s = lane & 15;   // dim segment 0..15

  f4_t* row4 = (f4_t*)(out_adj + (size_t)r * NN);
  const f4_t z = {0.f, 0.f, 0.f, 0.f};

  double grb[8], aa[8], w0c[8], w1c[8];
  const double* gr = g + (size_t)r * HH + s * 8;
#pragma unroll
  for (int d = 0; d < 8; d++) {
    int dim = s * 8 + d;
    grb[d] = gr[d] + (double)b1[dim];
    aa[d]  = (double)pa[dim];
    w0c[d] = (double)W2[2 * dim];
    w1c[d] = (double)W2[2 * dim + 1];
  }

  const int* nrow = nbr + r * KK;
  double st0 = 0.0, st1 = 0.0;
  for (int grp = 0; grp < 16; grp++) {
    // interleaved zero-fill: 2 nt float4 stores per lane per iteration
    __builtin_nontemporal_store(z, row4 + lane + (2 * grp) * 64);
    __builtin_nontemporal_store(z, row4 + lane + (2 * grp + 1) * 64);

    int c = nrow[grp * 4 + q];
    const double* gc = g + (size_t)c * HH + s * 8;
    double t0 = 0.0, t1 = 0.0;
#pragma unroll
    for (int d = 0; d < 8; d++) {
      double h = grb[d] - gc[d];
      h = h >= 0.0 ? h : aa[d] * h;
      t0 += h * w0c[d];
      t1 += h * w1c[d];
    }
#pragma unroll
    for (int m = 1; m < 16; m <<= 1) {
      t0 += __shfl_xor(t0, m, 16);
      t1 += __shfl_xor(t1, m, 16);
    }
    if (s == grp) { st0 = t0; st1 = t1; }  // lane q*16+grp keeps edge grp*4+q
  }
  int src = ((lane & 3) << 4) | (lane >> 2);
  double T0 = __shfl(st0, src, 64);
  double T1 = __shfl(st1, src, 64);
  double l0 = T0 + (double)b2[0];
  double l1 = T1 + (double)b2[1];
  size_t e = (size_t)r * KK + lane;
  int c = nrow[lane];
  p1d[e] = l1 - l0;                    // rank key (monotone in p1)
  float dm = (float)(l0 > l1 ? l0 : l1);
  float e0 = expf((float)l0 - dm), e1 = expf((float)l1 - dm);
  float inv = 1.0f / (e0 + e1);
  *(float2*)(out_prob + 2 * e) = make_float2(e0 * inv, e1 * inv);
  *(float2*)(out_pair + 2 * e) = make_float2((float)r, (float)c);
}

// ---------------------------------------------------------------------------
// k_rank: one wave per row (4 rows/block). Stable ascending rank of d
// (ties by index = jnp stable argsort), keep rank>=32, degree-normalize,
// scatter into the pre-zeroed new_adj row, emit left_row.
// ---------------------------------------------------------------------------
__global__ __launch_bounds__(256) void k_rank(
    const double* __restrict__ p1d, const int* __restrict__ nbr,
    const float* __restrict__ adj, float* __restrict__ out_adj,
    float* __restrict__ out_left) {
  int wave = threadIdx.x >> 6;
  int lane = threadIdx.x & 63;
  int r = blockIdx.x * 4 + wave;
  __shared__ double sp[4][64];
  __shared__ double sv[4][64];
  double p = p1d[(size_t)r * KK + lane];
  sp[wave][lane] = p;
  int c = nbr[r * KK + lane];
  float v = __builtin_nontemporal_load(&adj[(size_t)r * NN + c]);
  __syncthreads();
  int rank = 0;
#pragma unroll 8
  for (int j = 0; j < KK; j++) {
    double qq = sp[wave][j];
    rank += (int)((qq < p) || (qq == p && j < lane));
  }
  bool kept = rank >= SET0V;
  sv[wave][lane] = kept ? (double)v : 0.0;
  __syncthreads();
  double deg = 0.0;
#pragma unroll 8
  for (int j = 0; j < KK; j++) deg += sv[wave][j];
  if (kept) {
    out_adj[(size_t)r * NN + c] = (float)((double)v / (deg + 1e-6));
    out_left[(size_t)r * SET0V + (rank - SET0V)] = (float)(r * KK + lane);
  }
}

extern "C" void kernel_launch(void* const* d_in, const int* in_sizes, int n_in,
                              void* d_out, int out_size, void* d_ws, size_t ws_size,
                              hipStream_t stream) {
  const float* adj  = (const float*)d_in[0];
  const float* feat = (const float*)d_in[1];
  const int*   nbr  = (const int*)d_in[2];
  const float* W1   = (const float*)d_in[4];
  const float* b1   = (const float*)d_in[5];
  const float* pa   = (const float*)d_in[6];
  const float* W2   = (const float*)d_in[7];
  const float* b2   = (const float*)d_in[8];
  float* out = (float*)d_out;

  double* g   = (double*)d_ws;           // 8192*128 doubles = 8 MiB
  double* p1d = g + (size_t)NN * HH;     // 524288 doubles   = 4 MiB

  hipLaunchKernelGGL(k_g, dim3(1024), dim3(128), 0, stream,
                     feat, W1, g, (f4_t*)(out + OFF_FEAT), out + OFF_BEF);
  hipLaunchKernelGGL(k_edge, dim3(2048), dim3(256), 0, stream,
                     g, nbr, b1, b2, pa, W2,
                     p1d, out + OFF_PROB, out + OFF_PAIR, out + OFF_ADJ);
  hipLaunchKernelGGL(k_rank, dim3(2048), dim3(256), 0, stream,
                     p1d, nbr, adj, out + OFF_ADJ, out + OFF_LEFT);
}

// Round 5
// 494.163 us; speedup vs baseline: 1.3121x; 1.0384x over previous
//
#include <hip/hip_runtime.h>
#include <cmath>

#define NN 8192
#define KK 64
#define DD 256
#define HH 128
#define SET0V 32
#define EE (NN*KK)

typedef float f4_t __attribute__((ext_vector_type(4)));

static constexpr size_t OFF_ADJ  = 0;
static constexpr size_t OFF_FEAT = (size_t)NN * NN;             // 67108864
static constexpr size_t OFF_PROB = OFF_FEAT + (size_t)NN * DD;  // 69206016
static constexpr size_t OFF_PAIR = OFF_PROB + (size_t)EE * 2;   // 70254592
static constexpr size_t OFF_BEF  = OFF_PAIR + (size_t)EE * 2;   // 71303168
static constexpr size_t OFF_AFT  = OFF_BEF + 1;                 // 71303169
static constexpr size_t OFF_LEFT = OFF_AFT + 1;                 // 71303170

// ---------------------------------------------------------------------------
// k_g: g = feat @ W1 in fp64 ([8192,256]x[256,128] -> [8192,128] doubles),
// plus feat copy-out (non-temporal) and the two scalar outputs.
// 1024 blocks x 128 threads, 8 rows per block.
// ---------------------------------------------------------------------------
__global__ __launch_bounds__(128) void k_g(const float* __restrict__ feat,
                                           const float* __restrict__ W1,
                                           double* __restrict__ g,
                                           f4_t* __restrict__ out_feat,
                                           float* __restrict__ out_scal) {
  __shared__ float sf[8 * DD];  // 8 KiB
  int j = threadIdx.x;          // 0..127 = output col
  int n0 = blockIdx.x * 8;
  const f4_t* fsrc = (const f4_t*)(feat + (size_t)n0 * DD);
  f4_t* fdst = (f4_t*)sf;
  f4_t* odst = out_feat + (size_t)n0 * DD / 4;
#pragma unroll
  for (int t = 0; t < 4; t++) {
    f4_t v = fsrc[j + t * 128];
    fdst[j + t * 128] = v;
    __builtin_nontemporal_store(v, odst + j + t * 128);  // fused feat copy-out
  }
  if (blockIdx.x == 0 && j == 0) {
    out_scal[0] = 64.0f;  // before_edge_num
    out_scal[1] = 32.0f;  // after_edge_num (kept vals >= 0.1, never zero)
  }
  __syncthreads();
  double acc[8];
#pragma unroll
  for (int n = 0; n < 8; n++) acc[n] = 0.0;
  for (int k = 0; k < DD; k += 4) {
    double w0 = (double)W1[(k + 0) * HH + j];
    double w1 = (double)W1[(k + 1) * HH + j];
    double w2 = (double)W1[(k + 2) * HH + j];
    double w3 = (double)W1[(k + 3) * HH + j];
#pragma unroll
    for (int n = 0; n < 8; n++) {
      f4_t f = *(const f4_t*)&sf[n * DD + k];
      acc[n] += (double)f.x * w0;
      acc[n] += (double)f.y * w1;
      acc[n] += (double)f.z * w2;
      acc[n] += (double)f.w * w3;
    }
  }
#pragma unroll
  for (int n = 0; n < 8; n++) g[(size_t)(n0 + n) * HH + j] = acc[n];
}

// ---------------------------------------------------------------------------
// k_main: fully fused per-row pipeline. One wave per dst row (4 rows/block):
//   - early issue: nbr row + adj[r][c] gather (latency hides under MLP)
//   - interleaved nt zero-fill of the 32 KB new_adj row
//   - per-edge MLP in fp64 (16 lanes/edge, coalesced g gathers, butterfly)
//   - rank key d = l1-l0 (fp64, monotone in p1, identical order & ties)
//   - stable rank via LDS, keep rank>=32, fp64 degree, scatter normalized
//     values into the row this same wave just zeroed, emit left_row.
// WAW safety: __syncthreads() lowers to s_waitcnt vmcnt(0)+s_barrier on
// gfx950, so the nt zero stores are drained before the scatter stores.
// ---------------------------------------------------------------------------
__global__ __launch_bounds__(256) void k_main(
    const double* __restrict__ g, const int* __restrict__ nbr,
    const float* __restrict__ b1, const float* __restrict__ b2,
    const float* __restrict__ pa, const float* __restrict__ W2,
    const float* __restrict__ adj, float* __restrict__ out_adj,
    float* __restrict__ out_prob, float* __restrict__ out_pair,
    float* __restrict__ out_left) {
  int wave = threadIdx.x >> 6;
  int lane = threadIdx.x & 63;
  int r = blockIdx.x * 4 + wave;
  int q = lane >> 4;   // edge slot 0..3
  int s = lane & 15;   // dim segment 0..15

  const int* nrow = nbr + r * KK;
  int c_mine = nrow[lane];                                   // early issue
  float v = __builtin_nontemporal_load(&adj[(size_t)r * NN + c_mine]);  // early

  f4_t* row4 = (f4_t*)(out_adj + (size_t)r * NN);
  const f4_t z = {0.f, 0.f, 0.f, 0.f};

  double grb[8], aa[8], w0c[8], w1c[8];
  const double* gr = g + (size_t)r * HH + s * 8;
#pragma unroll
  for (int d = 0; d < 8; d++) {
    int dim = s * 8 + d;
    grb[d] = gr[d] + (double)b1[dim];
    aa[d]  = (double)pa[dim];
    w0c[d] = (double)W2[2 * dim];
    w1c[d] = (double)W2[2 * dim + 1];
  }

  double st0 = 0.0, st1 = 0.0;
  for (int grp = 0; grp < 16; grp++) {
    // interleaved zero-fill: 2 nt float4 stores per lane per iteration
    __builtin_nontemporal_store(z, row4 + lane + (2 * grp) * 64);
    __builtin_nontemporal_store(z, row4 + lane + (2 * grp + 1) * 64);

    int c = nrow[grp * 4 + q];
    const double* gc = g + (size_t)c * HH + s * 8;
    double t0 = 0.0, t1 = 0.0;
#pragma unroll
    for (int d = 0; d < 8; d++) {
      double h = grb[d] - gc[d];
      h = h >= 0.0 ? h : aa[d] * h;
      t0 += h * w0c[d];
      t1 += h * w1c[d];
    }
#pragma unroll
    for (int m = 1; m < 16; m <<= 1) {
      t0 += __shfl_xor(t0, m, 16);
      t1 += __shfl_xor(t1, m, 16);
    }
    if (s == grp) { st0 = t0; st1 = t1; }  // lane q*16+grp keeps edge grp*4+q
  }
  int src = ((lane & 3) << 4) | (lane >> 2);
  double T0 = __shfl(st0, src, 64);
  double T1 = __shfl(st1, src, 64);
  double l0 = T0 + (double)b2[0];
  double l1 = T1 + (double)b2[1];
  double dkey = l1 - l0;               // rank key (monotone in p1)

  // prob / pair outputs (coalesced float2)
  size_t e = (size_t)r * KK + lane;
  float dm = (float)(l0 > l1 ? l0 : l1);
  float e0 = expf((float)l0 - dm), e1 = expf((float)l1 - dm);
  float inv = 1.0f / (e0 + e1);
  *(float2*)(out_prob + 2 * e) = make_float2(e0 * inv, e1 * inv);
  *(float2*)(out_pair + 2 * e) = make_float2((float)r, (float)c_mine);

  // stable ascending rank (ties by index = jnp stable argsort)
  __shared__ double sp[4][64];
  __shared__ double sv[4][64];
  sp[wave][lane] = dkey;
  __syncthreads();  // also drains nt zero stores (vmcnt(0) before s_barrier)
  int rank = 0;
#pragma unroll 8
  for (int j = 0; j < KK; j++) {
    double qq = sp[wave][j];
    rank += (int)((qq < dkey) || (qq == dkey && j < lane));
  }
  bool kept = rank >= SET0V;
  sv[wave][lane] = kept ? (double)v : 0.0;
  __syncthreads();
  double deg = 0.0;
#pragma unroll 8
  for (int j = 0; j < KK; j++) deg += sv[wave][j];
  if (kept) {
    out_adj[(size_t)r * NN + c_mine] = (float)((double)v / (deg + 1e-6));
    out_left[(size_t)r * SET0V + (rank - SET0V)] = (float)(r * KK + lane);
  }
}

extern "C" void kernel_launch(void* const* d_in, const int* in_sizes, int n_in,
                              void* d_out, int out_size, void* d_ws, size_t ws_size,
                              hipStream_t stream) {
  const float* adj  = (const float*)d_in[0];
  const float* feat = (const float*)d_in[1];
  const int*   nbr  = (const int*)d_in[2];
  const float* W1   = (const float*)d_in[4];
  const float* b1   = (const float*)d_in[5];
  const float* pa   = (const float*)d_in[6];
  const float* W2   = (const float*)d_in[7];
  const float* b2   = (const float*)d_in[8];
  float* out = (float*)d_out;

  double* g = (double*)d_ws;  // 8192*128 doubles = 8 MiB

  hipLaunchKernelGGL(k_g, dim3(1024), dim3(128), 0, stream,
                     feat, W1, g, (f4_t*)(out + OFF_FEAT), out + OFF_BEF);
  hipLaunchKernelGGL(k_main, dim3(2048), dim3(256), 0, stream,
                     g, nbr, b1, b2, pa, W2, adj,
                     out + OFF_ADJ, out + OFF_PROB, out + OFF_PAIR,
                     out + OFF_LEFT);
}